// Round 3
// baseline (130.101 us; speedup 1.0000x reference)
//
#include <hip/hip_runtime.h>

// ThinPlateSpline: out = K_query @ rbf_weights + P_query @ poly_coeffs
//   K_ij = r*ln(r), r = ||u_i - c_j|| (d=3)
//   kk = sqrt(r2) * log2(r2) * C, C = 0.5*ln2 folded into staged weights.
//
// R16: structural rebuild. R13-R15 all carried ~50-60 cyc/group of fixed
// overhead: wave-uniform ds_read_b128 of j-records (~12cyc each) for data
// identical across lanes, 20.5KB LDS pinning occupancy at the 8-block edge
// (measured OccupancyPercent 36% -> dep chains exposed), and a
// reduction+syncthreads tail protecting cheap L2-resident atomics.
// This round: per-wave QUERY ownership (no reduction), j-records
// precomputed into workspace by a prep kernel and read via wave-uniform
// index -> s_load_dwordx8 into SGPRs (each v_fma reads exactly 1 SGPR:
// legal). Zero LDS, zero syncthreads. Math = R13 (hw sqrt + hw log, the
// fastest measured). Inner loop: 9 VALU + 2 trans per pair, nothing else.
// Static per SIMD: 9216 VALU (7.7us) + 2048 trans (7-14us), overlapping.
// Predicted kernel 38 -> 17-23us, bench ~65-72us, absmax 0.125.
// If trans-bound in counters, R17 swaps log to the VALU poly.

typedef float v4f __attribute__((ext_vector_type(4)));

#define BLK 256
#define QPT 4              // queries per lane
#define QPW (64 * QPT)     // queries per wave = 256
#define NWV 4              // waves per block
#define QPB (QPW * NWV)    // queries per block = 1024
#define JBLK 32            // j's per block (grid.y slice)

// rec[j] = {-2cx,-2cy,-2cz,c2, Cwx,Cwy,Cwz,0}  (8 floats, 32B)
__global__ void tps_prep(const float* __restrict__ cp,
                         const float* __restrict__ w,
                         float* __restrict__ rec, int n)
{
    const float C = 0.34657359027997264f;  // 0.5 * ln(2)
    const int j = blockIdx.x * blockDim.x + threadIdx.x;
    if (j >= n) return;
    const float cx = cp[j * 3 + 0], cy = cp[j * 3 + 1], cz = cp[j * 3 + 2];
    v4f a = {-2.f * cx, -2.f * cy, -2.f * cz,
             fmaf(cx, cx, fmaf(cy, cy, cz * cz))};
    v4f b = {C * w[j * 3 + 0], C * w[j * 3 + 1], C * w[j * 3 + 2], 0.f};
    ((v4f*)rec)[j * 2 + 0] = a;
    ((v4f*)rec)[j * 2 + 1] = b;
}

__global__ __launch_bounds__(BLK, 8) void tps_kernel(
    const float* __restrict__ u,     // (batch, 3)
    const float* __restrict__ rec,   // (n, 8) staged records
    const float* __restrict__ poly,  // (4, 3)
    float* __restrict__ out,         // (batch, 3)
    int batch, int n)
{
    const int tid  = threadIdx.x;
    const int lane = tid & 63;
    const int wv   = tid >> 6;
    const int q0   = blockIdx.x * QPB + wv * QPW + lane;

    float ux[QPT], uy[QPT], uz[QPT], usq[QPT];
    float ax[QPT], ay[QPT], az[QPT];
#pragma unroll
    for (int k = 0; k < QPT; ++k) {
        const int q = q0 + k * 64;
        ux[k] = u[q * 3 + 0];
        uy[k] = u[q * 3 + 1];
        uz[k] = u[q * 3 + 2];
        usq[k] = fmaf(ux[k], ux[k], fmaf(uy[k], uy[k], uz[k] * uz[k]));
        ax[k] = 0.f; ay[k] = 0.f; az[k] = 0.f;
    }

    if (blockIdx.y == 0) {  // polynomial term exactly once per query
#pragma unroll
        for (int k = 0; k < QPT; ++k) {
            ax[k] = poly[0] + ux[k] * poly[3] + uy[k] * poly[6] + uz[k] * poly[9];
            ay[k] = poly[1] + ux[k] * poly[4] + uy[k] * poly[7] + uz[k] * poly[10];
            az[k] = poly[2] + ux[k] * poly[5] + uy[k] * poly[8] + uz[k] * poly[11];
        }
    }

    const v4f* __restrict__ rec4 = (const v4f*)rec;
    const int j0 = blockIdx.y * JBLK;
#pragma unroll 2
    for (int j = j0; j < j0 + JBLK; ++j) {
        // wave-uniform index -> s_load_dwordx8 into SGPRs
        const v4f A = rec4[j * 2 + 0];  // {-2cx,-2cy,-2cz,c2}
        const v4f B = rec4[j * 2 + 1];  // {Cwx,Cwy,Cwz,0}
#pragma unroll
        for (int k = 0; k < QPT; ++k) {
            float r2 = fmaf(A.x, ux[k],
                       fmaf(A.y, uy[k],
                       fmaf(A.z, uz[k], A.w + usq[k])));
            r2 = fmaxf(r2, 1e-30f);
            const float sq = __builtin_amdgcn_sqrtf(r2);   // trans pipe
            const float lg = __builtin_amdgcn_logf(r2);    // trans pipe
            const float kk = sq * lg;                      // *C in B
            ax[k] = fmaf(kk, B.x, ax[k]);
            ay[k] = fmaf(kk, B.y, ay[k]);
            az[k] = fmaf(kk, B.z, az[k]);
        }
    }

    // Direct device-scope atomics: out is 196KB (L2-resident);
    // each address receives grid.y=128 adds spread over the kernel.
#pragma unroll
    for (int k = 0; k < QPT; ++k) {
        const int q = q0 + k * 64;
        atomicAdd(&out[q * 3 + 0], ax[k]);
        atomicAdd(&out[q * 3 + 1], ay[k]);
        atomicAdd(&out[q * 3 + 2], az[k]);
    }
}

extern "C" void kernel_launch(void* const* d_in, const int* in_sizes, int n_in,
                              void* d_out, int out_size, void* d_ws, size_t ws_size,
                              hipStream_t stream) {
    const float* u    = (const float*)d_in[0];  // (batch,3)
    const float* cp   = (const float*)d_in[1];  // (n,3)
    const float* w    = (const float*)d_in[2];  // (n,3)
    const float* poly = (const float*)d_in[3];  // (4,3)
    float* out = (float*)d_out;
    float* rec = (float*)d_ws;                  // n*8 floats = 128KB

    const int batch = in_sizes[0] / 3;  // 16384
    const int n     = in_sizes[1] / 3;  // 4096

    hipMemsetAsync(d_out, 0, (size_t)out_size * sizeof(float), stream);

    tps_prep<<<dim3((n + BLK - 1) / BLK), dim3(BLK), 0, stream>>>(cp, w, rec, n);

    dim3 block(BLK);
    dim3 grid(batch / QPB, n / JBLK);   // (16, 128) = 2048 blocks
    tps_kernel<<<grid, block, 0, stream>>>(u, rec, poly, out, batch, n);
}

// Round 4
// 81.150 us; speedup vs baseline: 1.6032x; 1.6032x over previous
//
#include <hip/hip_runtime.h>

// ThinPlateSpline: out = K_query @ rbf_weights + P_query @ poly_coeffs
//   K_ij = r*ln(r), r = ||u_i - c_j|| (d=3)
//   kk = sqrt(r2) * log2(r2) * C, C = 0.5*ln2 folded into staged weights.
//
// R17: back to the proven R13 structure (33us, best measured), attacking
// IDLE not pipe throughput. Evidence: R16 (s_load recs + raw atomics) =
// 74us at 24% VALUBusy -> latency-bound, and its WRITE_SIZE hit 72MB from
// un-reduced atomics; R13<->R15 comparison shows hw trans is cheap (~8cyc
// quarter-rate, pipelined, overlaps across waves) so evicting it to VALU
// polynomials was misguided. Changes vs R13:
//   - scalar math, no v2f packing (packed f32 showed no throughput gain:
//     VALU-busy ~= 2x packed static count in R14/R16; packing only added
//     shuffle movs). QPT=4 scalar chains = ILP 4.
//   - un-duplicated LDS records: 2 ds_read_b128/j instead of 4; LDS
//     20.5 -> 16.25 KB, LDS occupancy bound 7 -> 9 blocks/CU (no longer
//     binding vs the 8-block wave cap).
//   - #pragma unroll 4 so the compiler batches broadcast LDS reads ahead.
// Static busy floor ~7.7-14.5us/SIMD. Predicted kernel 20-26us, bench
// ~68-74us, WRITE_SIZE back to ~6MB, VALUBusy >=55%, absmax 0.125.
// Structure: BLK=256 (4 waves = 4 n-splits), JCHUNK=128, grid (64,32) =
// 2048 blocks = 8 resident blocks/CU, in-block LDS reduction, coalesced
// atomics across grid.y.

typedef float v4f __attribute__((ext_vector_type(4)));

#define BLK 256
#define NS 4            // waves per block = in-block n-splits
#define QPT 4           // queries per lane
#define QPB 256         // queries per block = 64 * QPT
#define JCHUNK 128      // j per block
#define JW (JCHUNK / NS)

__global__ __launch_bounds__(BLK, 8) void tps_kernel(
    const float* __restrict__ u,     // (batch, 3)
    const float* __restrict__ cp,    // (n, 3)
    const float* __restrict__ w,     // (n, 3)
    const float* __restrict__ poly,  // (4, 3)
    float* __restrict__ out,         // (batch, 3)
    int batch, int n)
{
    // s_a[j] = {-2cx,-2cy,-2cz,c2}   s_b[j] = {Cwx,Cwy,Cwz,0}
    __shared__ v4f s_a[JCHUNK];            // 2 KB
    __shared__ v4f s_b[JCHUNK];            // 2 KB
    __shared__ float s_red[NS][QPB * 3];   // 12 KB per-wave partials

    const float C = 0.34657359027997264f;  // 0.5 * ln(2)

    const int tid = threadIdx.x;
    const int j0 = blockIdx.y * JCHUNK;

    if (tid < JCHUNK) {  // stage + transform this 128-j slice
        const int g = j0 + tid;
        const float cx = cp[g * 3 + 0], cy = cp[g * 3 + 1], cz = cp[g * 3 + 2];
        s_a[tid] = (v4f){-2.f * cx, -2.f * cy, -2.f * cz,
                         fmaf(cx, cx, fmaf(cy, cy, cz * cz))};
        s_b[tid] = (v4f){C * w[g * 3 + 0], C * w[g * 3 + 1],
                         C * w[g * 3 + 2], 0.f};
    }
    __syncthreads();

    const int lane = tid & 63;
    const int wv   = tid >> 6;    // 0..3 = n-split
    const int q0   = blockIdx.x * QPB + lane;   // queries q0 + k*64

    float ux[QPT], uy[QPT], uz[QPT], us[QPT];
    float ax[QPT], ay[QPT], az[QPT];
#pragma unroll
    for (int k = 0; k < QPT; ++k) {
        const int q = q0 + k * 64;
        ux[k] = u[q * 3 + 0];
        uy[k] = u[q * 3 + 1];
        uz[k] = u[q * 3 + 2];
        us[k] = fmaf(ux[k], ux[k], fmaf(uy[k], uy[k], uz[k] * uz[k]));
        ax[k] = 0.f; ay[k] = 0.f; az[k] = 0.f;
    }

    if (blockIdx.y == 0 && wv == 0) {  // polynomial term exactly once
#pragma unroll
        for (int k = 0; k < QPT; ++k) {
            ax[k] = poly[0] + ux[k] * poly[3] + uy[k] * poly[6] + uz[k] * poly[9];
            ay[k] = poly[1] + ux[k] * poly[4] + uy[k] * poly[7] + uz[k] * poly[10];
            az[k] = poly[2] + ux[k] * poly[5] + uy[k] * poly[8] + uz[k] * poly[11];
        }
    }

    const int jlo = wv * JW;
#pragma unroll 4
    for (int j = jlo; j < jlo + JW; ++j) {
        const v4f A = s_a[j];   // broadcast ds_read_b128
        const v4f B = s_b[j];   // broadcast ds_read_b128
#pragma unroll
        for (int k = 0; k < QPT; ++k) {
            float r2 = fmaf(A.x, ux[k],
                       fmaf(A.y, uy[k],
                       fmaf(A.z, uz[k], A.w + us[k])));
            r2 = fmaxf(r2, 1e-30f);
            const float sq = __builtin_amdgcn_sqrtf(r2);   // trans pipe
            const float lg = __builtin_amdgcn_logf(r2);    // trans pipe
            const float kk = sq * lg;                      // *C in B
            ax[k] = fmaf(kk, B.x, ax[k]);
            ay[k] = fmaf(kk, B.y, ay[k]);
            az[k] = fmaf(kk, B.z, az[k]);
        }
    }

    // In-block reduction across the 4 n-split waves.
#pragma unroll
    for (int k = 0; k < QPT; ++k) {
        const int b = (k * 64 + lane) * 3;
        s_red[wv][b + 0] = ax[k];
        s_red[wv][b + 1] = ay[k];
        s_red[wv][b + 2] = az[k];
    }
    __syncthreads();

    for (int v = tid; v < QPB * 3; v += BLK) {
        float s = s_red[0][v] + s_red[1][v] + s_red[2][v] + s_red[3][v];
        atomicAdd(&out[(size_t)blockIdx.x * (QPB * 3) + v], s);
    }
}

extern "C" void kernel_launch(void* const* d_in, const int* in_sizes, int n_in,
                              void* d_out, int out_size, void* d_ws, size_t ws_size,
                              hipStream_t stream) {
    const float* u    = (const float*)d_in[0];  // (batch,3)
    const float* cp   = (const float*)d_in[1];  // (n,3)
    const float* w    = (const float*)d_in[2];  // (n,3)
    const float* poly = (const float*)d_in[3];  // (4,3)
    float* out = (float*)d_out;

    const int batch = in_sizes[0] / 3;  // 16384
    const int n     = in_sizes[1] / 3;  // 4096

    hipMemsetAsync(d_out, 0, (size_t)out_size * sizeof(float), stream);

    dim3 block(BLK);
    dim3 grid(batch / QPB, n / JCHUNK);  // (64, 32) = 2048 blocks
    tps_kernel<<<grid, block, 0, stream>>>(u, cp, w, poly, out, batch, n);
}

// Round 5
// 79.591 us; speedup vs baseline: 1.6346x; 1.0196x over previous
//
#include <hip/hip_runtime.h>

// ThinPlateSpline: out = K_query @ rbf_weights + P_query @ poly_coeffs
//   K_ij = r*ln(r), r = ||u_i - c_j|| (d=3)
//   kk = sqrt(r2) * log2(r2) * C, C = 0.5*ln2 folded into staged weights.
//
// R18: R13 body (best measured, 33us: packed v2f, duplicated LDS records,
// hw sqrt + hw log) + LDS UNION to kill the resident-block straggler.
// Evidence: R13/R14/R15 LDS = staging 8KB + s_red 12KB = 20.5KB -> only 7
// blocks/CU resident vs grid's 8/CU -> every CU runs a 7-block generation
// then ONE straggler block (4 waves, no co-tenants, latency fully exposed)
// ~= the persistent ~40-50% idle and measured 36-44% OccupancyPercent.
// Staging arrays and s_red are never live simultaneously (staging read only
// in main loop; s_red written only after) -> union them: LDS 20.5 -> 12.3KB,
// block residency bound moves to the wave cap (8 blocks = 32 waves = 100%),
// all 2048 blocks co-resident in one generation. Costs one extra
// __syncthreads between last staging read and first s_red write.
// R14-R17 lesson baked in: per-pair math cost is fixed (~8-9 VALU + 2 trans,
// any spelling); only idle-removal moves the needle now.
// Predicted kernel 27-29us, bench ~73-76us, LDS_Block_Size ~12.5KB,
// OccupancyPercent >=55, absmax 0.125.

typedef float v2f __attribute__((ext_vector_type(2)));
typedef float v4f __attribute__((ext_vector_type(4)));

#define BLK 256
#define NS 4            // waves per block = in-block n-splits
#define QPT 4           // queries per lane = 2 packed groups
#define QPB 256         // queries per block = 64 * QPT
#define JCHUNK 128      // j per block
#define JW (JCHUNK / NS)

union SmemT {
    struct {
        v4f a4[JCHUNK * 2];   // {-2cx,-2cx,-2cy,-2cy}, {-2cz,-2cz,c2,c2}
        v4f b4[JCHUNK * 2];   // {Cwx,Cwx,Cwy,Cwy},     {Cwz,Cwz,0,0}
    } st;                      // 8 KB, live during main loop only
    float red[NS][QPB * 3];    // 12 KB, live during epilogue only
};

__global__ __launch_bounds__(BLK, 8) void tps_kernel(
    const float* __restrict__ u,     // (batch, 3)
    const float* __restrict__ cp,    // (n, 3)
    const float* __restrict__ w,     // (n, 3)
    const float* __restrict__ poly,  // (4, 3)
    float* __restrict__ out,         // (batch, 3)
    int batch, int n)
{
    __shared__ SmemT sm;             // 12.3 KB total (union)

    const float C = 0.34657359027997264f;  // 0.5 * ln(2)

    const int tid = threadIdx.x;
    const int j0 = blockIdx.y * JCHUNK;

    if (tid < JCHUNK) {  // stage + transform + duplicate this 128-j slice
        const int g = j0 + tid;
        const float cx = cp[g * 3 + 0], cy = cp[g * 3 + 1], cz = cp[g * 3 + 2];
        const float c2 = fmaf(cx, cx, fmaf(cy, cy, cz * cz));
        const float wx = C * w[g * 3 + 0];
        const float wy = C * w[g * 3 + 1];
        const float wz = C * w[g * 3 + 2];
        sm.st.a4[tid * 2 + 0] = (v4f){-2.f * cx, -2.f * cx, -2.f * cy, -2.f * cy};
        sm.st.a4[tid * 2 + 1] = (v4f){-2.f * cz, -2.f * cz, c2, c2};
        sm.st.b4[tid * 2 + 0] = (v4f){wx, wx, wy, wy};
        sm.st.b4[tid * 2 + 1] = (v4f){wz, wz, 0.f, 0.f};
    }
    __syncthreads();

    const int lane = tid & 63;
    const int wv   = tid >> 6;    // 0..3 = n-split

    // 2 packed groups: group g holds queries (2g)*64+lane and (2g+1)*64+lane
    v2f uxv[2], uyv[2], uzv[2], usqv[2];
    v2f axv[2], ayv[2], azv[2];
#pragma unroll
    for (int g = 0; g < 2; ++g) {
        const int qa = blockIdx.x * QPB + (2 * g + 0) * 64 + lane;
        const int qb = blockIdx.x * QPB + (2 * g + 1) * 64 + lane;
        uxv[g] = (v2f){u[qa * 3 + 0], u[qb * 3 + 0]};
        uyv[g] = (v2f){u[qa * 3 + 1], u[qb * 3 + 1]};
        uzv[g] = (v2f){u[qa * 3 + 2], u[qb * 3 + 2]};
        usqv[g] = __builtin_elementwise_fma(uxv[g], uxv[g],
                  __builtin_elementwise_fma(uyv[g], uyv[g], uzv[g] * uzv[g]));
        axv[g] = (v2f){0.f, 0.f};
        ayv[g] = (v2f){0.f, 0.f};
        azv[g] = (v2f){0.f, 0.f};
    }

    if (blockIdx.y == 0 && wv == 0) {  // polynomial term exactly once
#pragma unroll
        for (int g = 0; g < 2; ++g) {
            axv[g] = poly[0] + uxv[g] * poly[3] + uyv[g] * poly[6] + uzv[g] * poly[9];
            ayv[g] = poly[1] + uxv[g] * poly[4] + uyv[g] * poly[7] + uzv[g] * poly[10];
            azv[g] = poly[2] + uxv[g] * poly[5] + uyv[g] * poly[8] + uzv[g] * poly[11];
        }
    }

    const int jlo = wv * JW;
#pragma unroll 2
    for (int j = jlo; j < jlo + JW; ++j) {
        const v4f A0 = sm.st.a4[j * 2 + 0];  // {ax,ax,ay,ay}
        const v4f A1 = sm.st.a4[j * 2 + 1];  // {az,az,c2,c2}
        const v4f B0 = sm.st.b4[j * 2 + 0];  // {wx,wx,wy,wy}
        const v4f B1 = sm.st.b4[j * 2 + 1];  // {wz,wz,0,0}
        const v2f m2x = A0.xy, m2y = A0.zw, m2z = A1.xy, c2v = A1.zw;
        const v2f wxv = B0.xy, wyv = B0.zw, wzv = B1.xy;
#pragma unroll
        for (int g = 0; g < 2; ++g) {
            v2f r2 = __builtin_elementwise_fma(m2x, uxv[g],
                     __builtin_elementwise_fma(m2y, uyv[g],
                     __builtin_elementwise_fma(m2z, uzv[g], c2v + usqv[g])));
            r2 = __builtin_elementwise_max(r2, (v2f){1e-30f, 1e-30f});
            // scalar hw trans per element (elementwise floor: 2 per pair)
            const v2f sq = {__builtin_amdgcn_sqrtf(r2.x),
                            __builtin_amdgcn_sqrtf(r2.y)};
            const v2f lg = {__builtin_amdgcn_logf(r2.x),
                            __builtin_amdgcn_logf(r2.y)};
            const v2f kk = sq * lg;      // v_pk_mul_f32
            axv[g] = __builtin_elementwise_fma(kk, wxv, axv[g]);
            ayv[g] = __builtin_elementwise_fma(kk, wyv, ayv[g]);
            azv[g] = __builtin_elementwise_fma(kk, wzv, azv[g]);
        }
    }

    // Staging arrays dead from here; re-use the LDS as s_red.
    __syncthreads();   // ensure ALL waves are done reading sm.st

    // In-block reduction across the 4 n-split waves.
#pragma unroll
    for (int g = 0; g < 2; ++g) {
        const int ba = ((2 * g + 0) * 64 + lane) * 3;
        const int bb = ((2 * g + 1) * 64 + lane) * 3;
        sm.red[wv][ba + 0] = axv[g].x;  sm.red[wv][bb + 0] = axv[g].y;
        sm.red[wv][ba + 1] = ayv[g].x;  sm.red[wv][bb + 1] = ayv[g].y;
        sm.red[wv][ba + 2] = azv[g].x;  sm.red[wv][bb + 2] = azv[g].y;
    }
    __syncthreads();

    for (int v = tid; v < QPB * 3; v += BLK) {
        float s = sm.red[0][v] + sm.red[1][v] + sm.red[2][v] + sm.red[3][v];
        atomicAdd(&out[(size_t)blockIdx.x * (QPB * 3) + v], s);
    }
}

extern "C" void kernel_launch(void* const* d_in, const int* in_sizes, int n_in,
                              void* d_out, int out_size, void* d_ws, size_t ws_size,
                              hipStream_t stream) {
    const float* u    = (const float*)d_in[0];  // (batch,3)
    const float* cp   = (const float*)d_in[1];  // (n,3)
    const float* w    = (const float*)d_in[2];  // (n,3)
    const float* poly = (const float*)d_in[3];  // (4,3)
    float* out = (float*)d_out;

    const int batch = in_sizes[0] / 3;  // 16384
    const int n     = in_sizes[1] / 3;  // 4096

    hipMemsetAsync(d_out, 0, (size_t)out_size * sizeof(float), stream);

    dim3 block(BLK);
    dim3 grid(batch / QPB, n / JCHUNK);  // (64, 32) = 2048 blocks
    tps_kernel<<<grid, block, 0, stream>>>(u, cp, w, poly, out, batch, n);
}